// Round 11
// baseline (98.513 us; speedup 1.0000x reference)
//
#include <hip/hip_runtime.h>
#include <hip/hip_bf16.h>

namespace {

constexpr int Bc = 2, Hc = 16, Lc = 2048, Dc = 128;
constexpr int KVBLK = 64;
constexpr int BH  = Bc * Hc;      // 32
constexpr int NKT = Lc / KVBLK;   // 32
constexpr int QB  = 128;          // q rows per block
constexpr int NQT = Lc / QB;      // 16
// 1/sqrt(128) * log2(e)  (softmax in exp2 domain)
constexpr float SCALE = 0.08838834764831845f * 1.4426950408889634f;

constexpr size_t ELEMS = (size_t)BH * Lc * Dc;        // 8.39M per tensor
constexpr size_t MLROWS = 2 * 8 * 32 * 128;           // part-major (m,l) rows

using f32x4   = __attribute__((ext_vector_type(4))) float;
using f32x16  = __attribute__((ext_vector_type(16))) float;
using short8  = __attribute__((ext_vector_type(8))) short;

union FragU { short8 v; short4 h[2]; };
union PFU  { short8 v; unsigned u[4]; };

// big-chains-first dispatch: g<8 full qt=g; 8..15 part0 qt=g; 16..23 part1 qt=g-8
__device__ const unsigned char g_map[24] = {
  7, 15, 23, 14, 22, 6, 13, 21, 12, 20, 5, 11,
  19, 10, 18, 4, 9, 17, 8, 16, 3, 2, 1, 0};

__device__ inline short f2bf(float f) {
  unsigned u = __builtin_bit_cast(unsigned, f);
  u += 0x7fffu + ((u >> 16) & 1u);          // RNE
  return (short)(u >> 16);
}

__device__ inline unsigned cvtpk(float a, float b) {
  __hip_bfloat162 h = __float22bfloat162_rn(float2{a, b});
  unsigned r;
  __builtin_memcpy(&r, &h, 4);
  return r;
}

__device__ inline void gload_lds16(const short* g, short* l) {
  __builtin_amdgcn_global_load_lds(
      (const __attribute__((address_space(1))) void*)g,
      (__attribute__((address_space(3))) void*)l, 16, 0, 0);
}

// ======== fused pre-pass: K and V fp32 -> bf16 in FRAGMENT-ORDERED tiles ========
__global__ __launch_bounds__(256) void conv_kv(const float* __restrict__ Kg,
                                               const float* __restrict__ Vg,
                                               short* __restrict__ Kw,
                                               short* __restrict__ Vw) {
  __shared__ short Vs[64 * 130];
  const int b = blockIdx.x;
  if (b < 4096) {
    int tid  = b * 256 + threadIdx.x;
    int rem  = tid & 1023;
    int tb   = tid >> 10;
    int ks   = rem >> 7;
    int s    = (rem >> 6) & 1;
    int lane = rem & 63;
    int hi   = lane >> 5, ln = lane & 31;
    const float* src = Kg + ((size_t)tb * 64 + s * 32 + ln) * 128 + ks * 16 + hi * 4;
    float4 a = *(const float4*)src;
    float4 c = *(const float4*)(src + 8);
    short8 v;
    v[0] = f2bf(a.x); v[1] = f2bf(a.y); v[2] = f2bf(a.z); v[3] = f2bf(a.w);
    v[4] = f2bf(c.x); v[5] = f2bf(c.y); v[6] = f2bf(c.z); v[7] = f2bf(c.w);
    *(short8*)(Kw + (size_t)tb * 8192 + rem * 8) = v;
  } else {
    int tb  = b - 4096;
    int tid = threadIdx.x;
    const float* vt = Vg + (size_t)tb * 8192;
#pragma unroll
    for (int p = 0; p < 8; ++p) {
      int g  = p * 256 + tid;
      int kv = g >> 5;
      int c4 = g & 31;
      float4 v = *((const float4*)vt + g);
      short* d = &Vs[kv * 130 + c4 * 4];
      d[0] = f2bf(v.x); d[1] = f2bf(v.y); d[2] = f2bf(v.z); d[3] = f2bf(v.w);
    }
    __syncthreads();
#pragma unroll
    for (int p = 0; p < 4; ++p) {
      int g    = p * 256 + tid;
      int nt   = g >> 8;
      int kc   = (g >> 6) & 3;
      int lane = g & 63;
      int hi   = lane >> 5, ln = lane & 31;
      int d    = nt * 32 + ln;
      int k0   = kc * 16 + hi * 4;
      short8 o;
#pragma unroll
      for (int j = 0; j < 4; ++j) o[j]     = Vs[(k0 + j)     * 130 + d];
#pragma unroll
      for (int j = 0; j < 4; ++j) o[4 + j] = Vs[(k0 + 8 + j) * 130 + d];
      *(short8*)(Vw + (size_t)tb * 8192 + g * 8) = o;
    }
  }
}

// ====== main attention: R8 skeleton + kv-split for long q-tiles ======
__global__ __launch_bounds__(256, 2) void attn_fwd11(
    const float* __restrict__ Qg, const short* __restrict__ Kw,
    const short* __restrict__ Vw, float* __restrict__ Og,
    float* __restrict__ Opart, float* __restrict__ Mbuf, float* __restrict__ Lbuf) {

  __shared__ __align__(16) short lds[2][2][8192];   // 64 KB -> 2 blocks/CU

  const int tid  = threadIdx.x;
  const int wave = tid >> 6;
  const int lane = tid & 63;
  const int hi   = lane >> 5;
  const int ln   = lane & 31;

  const int bid = blockIdx.x;
  const int bh  = bid & (BH - 1);             // bid%8 == bh%8 -> head-per-XCD L2 affinity
  const int g   = g_map[bid >> 5];

  int qt, t0, t1;
  if (g < 8)       { qt = g;     t0 = 0;      t1 = 2 * (qt + 1); }   // full (short)
  else if (g < 16) { qt = g;     t0 = 0;      t1 = qt + 1;       }   // part 0
  else             { qt = g - 8; t0 = qt + 1; t1 = 2 * (qt + 1); }   // part 1 (diag)
  const int ntloc = t1 - t0;
  const int q0w   = qt * QB + wave * 32;

  const float* Qp  = Qg + (size_t)bh * Lc * Dc;
  float*       Op  = Og + (size_t)bh * Lc * Dc;
  const short* Kwp = Kw + (size_t)bh * NKT * 8192;
  const short* Vwp = Vw + (size_t)bh * NKT * 8192;

  // ---- preload Q fragments (B-operand), pre-scaled ----
  short8 qf[8];
  {
    const float* qrow = Qp + (size_t)(q0w + ln) * Dc + hi * 4;
#pragma unroll
    for (int ks = 0; ks < 8; ++ks) {
      float4 a = *(const float4*)(qrow + ks * 16);
      float4 b = *(const float4*)(qrow + ks * 16 + 8);
      short8 v;
      v[0] = f2bf(a.x * SCALE); v[1] = f2bf(a.y * SCALE);
      v[2] = f2bf(a.z * SCALE); v[3] = f2bf(a.w * SCALE);
      v[4] = f2bf(b.x * SCALE); v[5] = f2bf(b.y * SCALE);
      v[6] = f2bf(b.z * SCALE); v[7] = f2bf(b.w * SCALE);
      qf[ks] = v;
    }
  }

  float m_run = -1e30f, l_run = 0.0f;
  f32x16 oacc[4];
#pragma unroll
  for (int nt = 0; nt < 4; ++nt)
#pragma unroll
    for (int r = 0; r < 16; ++r) oacc[nt][r] = 0.0f;

  auto stage = [&](int t, int b) {
    const short* gk = Kwp + (size_t)t * 8192 + tid * 8;
    const short* gv = Vwp + (size_t)t * 8192 + tid * 8;
    short* lk = &lds[b][0][tid * 8];
    short* lv = &lds[b][1][tid * 8];
#pragma unroll
    for (int i = 0; i < 4; ++i) gload_lds16(gk + i * 2048, lk + i * 2048);
#pragma unroll
    for (int i = 0; i < 4; ++i) gload_lds16(gv + i * 2048, lv + i * 2048);
  };

  auto rescale_if = [&](float mx) {
    if (!__all(mx - m_run <= 8.0f)) {         // defer-max THR=8 (rare path)
      float mnew = fmaxf(m_run, mx);
      float corr = exp2f(m_run - mnew);
      m_run = mnew;
      l_run *= corr;
#pragma unroll
      for (int r = 0; r < 16; ++r) {
        int qrow = (r & 3) + 8 * (r >> 2) + 4 * hi;
        float c = __shfl(corr, qrow);
#pragma unroll
        for (int nt = 0; nt < 4; ++nt) oacc[nt][r] *= c;
      }
    }
  };

  stage(t0, 0);

  for (int u = 0; u < ntloc; ++u) {
    const int t = t0 + u;
    const int cur = u & 1;
    __builtin_amdgcn_s_barrier();             // buf[cur^1] free
    if (u + 1 < ntloc) {
      stage(t + 1, cur ^ 1);
      asm volatile("s_waitcnt vmcnt(8)" ::: "memory");   // tile t landed (counted)
    } else {
      asm volatile("s_waitcnt vmcnt(0)" ::: "memory");
    }
    __builtin_amdgcn_s_barrier();             // tile t visible
    __builtin_amdgcn_sched_barrier(0);

    const int kv0 = t * KVBLK;
    if (q0w + 31 < kv0) continue;             // wave fully masked: stage-only

    const short* Kl = &lds[cur][0][lane * 8];
    const short* Vl = &lds[cur][1][lane * 8];

    // ---- QK(t): S^T = K*Q^T ----
    f32x16 s0, s1;
#pragma unroll
    for (int r = 0; r < 16; ++r) { s0[r] = 0.0f; s1[r] = 0.0f; }
    __builtin_amdgcn_s_setprio(1);
#pragma unroll
    for (int ks = 0; ks < 8; ++ks)
      s0 = __builtin_amdgcn_mfma_f32_32x32x16_bf16(
          *(const short8*)(Kl + ks * 1024), qf[ks], s0, 0, 0, 0);
#pragma unroll
    for (int ks = 0; ks < 8; ++ks)
      s1 = __builtin_amdgcn_mfma_f32_32x32x16_bf16(
          *(const short8*)(Kl + ks * 1024 + 512), qf[ks], s1, 0, 0, 0);
    __builtin_amdgcn_s_setprio(0);

    const bool diag = (kv0 + 63 > q0w);
    const int qg = q0w + ln;

    // =============== half 0: softmax + PV kc 0,1 ===============
    if (diag) {
#pragma unroll
      for (int r = 0; r < 16; ++r) {
        int kvr = kv0 + (r & 3) + 8 * (r >> 2) + 4 * hi;
        if (kvr > qg) s0[r] = -1e30f;
      }
    }
    {
      float ma = s0[0], mb = s0[4], mc = s0[8], md = s0[12];
#pragma unroll
      for (int r = 1; r < 4; ++r) {
        ma = fmaxf(ma, s0[r]);     mb = fmaxf(mb, s0[4 + r]);
        mc = fmaxf(mc, s0[8 + r]); md = fmaxf(md, s0[12 + r]);
      }
      float mx = fmaxf(fmaxf(ma, mb), fmaxf(mc, md));
      mx = fmaxf(mx, __shfl_xor(mx, 32));
      rescale_if(mx);
    }
    PFU pf0, pf1;
    {
      float rsa = 0.f, rsb = 0.f;
#pragma unroll
      for (int e2 = 0; e2 < 4; ++e2) {
        float p00 = exp2f(s0[2 * e2]     - m_run);
        float p01 = exp2f(s0[2 * e2 + 1] - m_run);
        float p10 = exp2f(s0[8 + 2 * e2]     - m_run);
        float p11 = exp2f(s0[8 + 2 * e2 + 1] - m_run);
        rsa += p00 + p01;  rsb += p10 + p11;
        pf0.u[e2] = cvtpk(p00, p01);
        pf1.u[e2] = cvtpk(p10, p11);
      }
      float rs = rsa + rsb;
      rs += __shfl_xor(rs, 32);
      l_run += rs;
    }
    __builtin_amdgcn_s_setprio(1);
#pragma unroll
    for (int nt = 0; nt < 4; ++nt) {
      oacc[nt] = __builtin_amdgcn_mfma_f32_32x32x16_bf16(
          pf0.v, *(const short8*)(Vl + (nt * 4 + 0) * 512), oacc[nt], 0, 0, 0);
      oacc[nt] = __builtin_amdgcn_mfma_f32_32x32x16_bf16(
          pf1.v, *(const short8*)(Vl + (nt * 4 + 1) * 512), oacc[nt], 0, 0, 0);
    }
    __builtin_amdgcn_s_setprio(0);

    // =============== half 1: softmax + PV kc 2,3 ===============
    if (diag) {
#pragma unroll
      for (int r = 0; r < 16; ++r) {
        int kvr = kv0 + 32 + (r & 3) + 8 * (r >> 2) + 4 * hi;
        if (kvr > qg) s1[r] = -1e30f;
      }
    }
    {
      float ma = s1[0], mb = s1[4], mc = s1[8], md = s1[12];
#pragma unroll
      for (int r = 1; r < 4; ++r) {
        ma = fmaxf(ma, s1[r]);     mb = fmaxf(mb, s1[4 + r]);
        mc = fmaxf(mc, s1[8 + r]); md = fmaxf(md, s1[12 + r]);
      }
      float mx = fmaxf(fmaxf(ma, mb), fmaxf(mc, md));
      mx = fmaxf(mx, __shfl_xor(mx, 32));
      rescale_if(mx);
    }
    PFU pf2, pf3;
    {
      float rsa = 0.f, rsb = 0.f;
#pragma unroll
      for (int e2 = 0; e2 < 4; ++e2) {
        float p00 = exp2f(s1[2 * e2]     - m_run);
        float p01 = exp2f(s1[2 * e2 + 1] - m_run);
        float p10 = exp2f(s1[8 + 2 * e2]     - m_run);
        float p11 = exp2f(s1[8 + 2 * e2 + 1] - m_run);
        rsa += p00 + p01;  rsb += p10 + p11;
        pf2.u[e2] = cvtpk(p00, p01);
        pf3.u[e2] = cvtpk(p10, p11);
      }
      float rs = rsa + rsb;
      rs += __shfl_xor(rs, 32);
      l_run += rs;
    }
    __builtin_amdgcn_s_setprio(1);
#pragma unroll
    for (int nt = 0; nt < 4; ++nt) {
      oacc[nt] = __builtin_amdgcn_mfma_f32_32x32x16_bf16(
          pf2.v, *(const short8*)(Vl + (nt * 4 + 2) * 512), oacc[nt], 0, 0, 0);
      oacc[nt] = __builtin_amdgcn_mfma_f32_32x32x16_bf16(
          pf3.v, *(const short8*)(Vl + (nt * 4 + 3) * 512), oacc[nt], 0, 0, 0);
    }
    __builtin_amdgcn_s_setprio(0);
  }

  // ---- epilogue ----
  if (g < 8) {
    // full block: normalize and write O directly
    float linv = 1.0f / l_run;
#pragma unroll
    for (int r = 0; r < 16; ++r) {
      int qrow = (r & 3) + 8 * (r >> 2) + 4 * hi;
      float il = __shfl(linv, qrow);
      float* orow = Op + (size_t)(q0w + qrow) * Dc + ln;
#pragma unroll
      for (int nt = 0; nt < 4; ++nt)
        orow[nt * 32] = oacc[nt][r] * il;
    }
  } else {
    // split part: write unnormalized oacc + (m,l) per row
    const int part = (g < 16) ? 0 : 1;
    const int qtx  = qt - 8;
    float* Ob = Opart + (((size_t)part * 256 + qtx * 32 + bh) * 128) * 128;
#pragma unroll
    for (int r = 0; r < 16; ++r) {
      int qrow = (r & 3) + 8 * (r >> 2) + 4 * hi;
      float* orow = Ob + (size_t)(wave * 32 + qrow) * 128 + ln;
#pragma unroll
      for (int nt = 0; nt < 4; ++nt)
        orow[nt * 32] = oacc[nt][r];
    }
    if (hi == 0) {
      size_t ridx = ((size_t)part * 256 + qtx * 32 + bh) * 128 + wave * 32 + ln;
      Mbuf[ridx] = m_run;
      Lbuf[ridx] = l_run;
    }
  }
}

// ====== combine pass: merge the two kv-partials for qt>=8 ======
__global__ __launch_bounds__(256) void combine(
    const float* __restrict__ Opart, const float* __restrict__ Mbuf,
    const float* __restrict__ Lbuf, float* __restrict__ Og) {
  int idx = blockIdx.x * 256 + threadIdx.x;   // 1,048,576 (x4 floats each)
  int d4  = idx & 31;
  int row = (idx >> 5) & 127;
  int bh  = (idx >> 12) & 31;
  int qtx = idx >> 17;                        // 0..7 -> qt = qtx+8
  size_t rbase = ((size_t)qtx * 32 + bh) * 128 + row;
  size_t obase = rbase * 128 + d4 * 4;
  float4 a = *(const float4*)(Opart + obase);
  float4 b = *(const float4*)(Opart + (size_t)256 * 128 * 128 + obase);
  float ma = Mbuf[rbase], la = Lbuf[rbase];
  float mb = Mbuf[32768 + rbase], lb = Lbuf[32768 + rbase];
  float mS = fmaxf(ma, mb);
  float wa = exp2f(ma - mS), wb = exp2f(mb - mS);
  float inv = 1.0f / (la * wa + lb * wb);
  float4 o;
  o.x = (a.x * wa + b.x * wb) * inv;
  o.y = (a.y * wa + b.y * wb) * inv;
  o.z = (a.z * wa + b.z * wb) * inv;
  o.w = (a.w * wa + b.w * wb) * inv;
  *(float4*)(Og + (((size_t)bh * Lc) + (qtx + 8) * 128 + row) * Dc + d4 * 4) = o;
}

// ===================== fallback (ws too small): R1 kernel =====================
__device__ inline unsigned packbf(float a, float b) {
  return (unsigned)(unsigned short)f2bf(a) | ((unsigned)(unsigned short)f2bf(b) << 16);
}

__global__ __launch_bounds__(256, 2) void attn_fb(
    const float* __restrict__ Qg, const float* __restrict__ Kg,
    const float* __restrict__ Vg, float* __restrict__ Og) {
  __shared__ __align__(16) short Klds[KVBLK * Dc];
  __shared__ __align__(16) short Vt[Dc * 68];
  const int tid = threadIdx.x, wave = tid >> 6, lane = tid & 63;
  const int lg = lane >> 4, lr = lane & 15;
  const int bid = blockIdx.x;
  const int bh = bid & (BH - 1);
  const int qt = 31 - (bid >> 5);
  const int q0w = qt * 64 + wave * 16;
  const float* Qp = Qg + (size_t)bh * Lc * Dc;
  const float* Kp = Kg + (size_t)bh * Lc * Dc;
  const float* Vp = Vg + (size_t)bh * Lc * Dc;
  float* Op = Og + (size_t)bh * Lc * Dc;
  short8 qf[4];
  {
    const float* qrow = Qp + (size_t)(q0w + lr) * Dc;
#pragma unroll
    for (int dc = 0; dc < 4; ++dc) {
      float4 a = *(const float4*)(qrow + dc * 32 + lg * 4);
      float4 b = *(const float4*)(qrow + dc * 32 + 16 + lg * 4);
      short8 v;
      v[0]=f2bf(a.x*SCALE); v[1]=f2bf(a.y*SCALE); v[2]=f2bf(a.z*SCALE); v[3]=f2bf(a.w*SCALE);
      v[4]=f2bf(b.x*SCALE); v[5]=f2bf(b.y*SCALE); v[6]=f2bf(b.z*SCALE); v[7]=f2bf(b.w*SCALE);
      qf[dc] = v;
    }
  }
  const f32x4 zero4 = {0.f,0.f,0.f,0.f};
  float m_run = -1e30f, l_run = 0.0f;
  f32x4 oacc[8];
#pragma unroll
  for (int dt = 0; dt < 8; ++dt) oacc[dt] = zero4;
  const int ntiles = qt + 1, c4 = tid & 31, rK = tid >> 5;
  for (int t = 0; t < ntiles; ++t) {
    const int kv0 = t * KVBLK;
    __syncthreads();
#pragma unroll
    for (int p = 0; p < 8; ++p) {
      int row = rK + p * 8;
      float4 k4 = *(const float4*)(Kp + (size_t)(kv0 + row) * Dc + c4 * 4);
      short4 pk; pk.x=f2bf(k4.x); pk.y=f2bf(k4.y); pk.z=f2bf(k4.z); pk.w=f2bf(k4.w);
      *(short4*)((char*)Klds + row * 256 + ((c4 * 8) ^ ((row & 7) << 4))) = pk;
    }
#pragma unroll
    for (int p = 0; p < 4; ++p) {
      int r0 = rK * 2 + p * 16;
      float4 v0 = *(const float4*)(Vp + (size_t)(kv0 + r0) * Dc + c4 * 4);
      float4 v1 = *(const float4*)(Vp + (size_t)(kv0 + r0 + 1) * Dc + c4 * 4);
      char* vb2 = (char*)Vt + r0 * 2;
      *(unsigned*)(vb2 + (c4*4+0)*136) = packbf(v0.x, v1.x);
      *(unsigned*)(vb2 + (c4*4+1)*136) = packbf(v0.y, v1.y);
      *(unsigned*)(vb2 + (c4*4+2)*136) = packbf(v0.z, v1.z);
      *(unsigned*)(vb2 + (c4*4+3)*136) = packbf(v0.w, v1.w);
    }
    __syncthreads();
    f32x4 st[4];
#pragma unroll
    for (int mt = 0; mt < 4; ++mt) st[mt] = zero4;
#pragma unroll
    for (int dc = 0; dc < 4; ++dc)
#pragma unroll
      for (int mt = 0; mt < 4; ++mt) {
        int row = mt * 16 + lr, sw2 = (row & 7) << 4;
        FragU a;
        a.h[0] = *(short4*)((char*)Klds + row*256 + ((dc*64      + lg*8) ^ sw2));
        a.h[1] = *(short4*)((char*)Klds + row*256 + ((dc*64 + 32 + lg*8) ^ sw2));
        st[mt] = __builtin_amdgcn_mfma_f32_16x16x32_bf16(a.v, qf[dc], st[mt], 0, 0, 0);
      }
    if (t == ntiles - 1) {
      const int qg = q0w + lr;
#pragma unroll
      for (int mt = 0; mt < 4; ++mt)
#pragma unroll
        for (int r = 0; r < 4; ++r)
          if (kv0 + mt * 16 + lg * 4 + r > qg) st[mt][r] = -1e30f;
    }
    float mx = st[0][0];
#pragma unroll
    for (int mt = 0; mt < 4; ++mt)
#pragma unroll
      for (int r = 0; r < 4; ++r) mx = fmaxf(mx, st[mt][r]);
    mx = fmaxf(mx, __shfl_xor(mx, 16));
    mx = fmaxf(mx, __shfl_xor(mx, 32));
    float mnew = fmaxf(m_run, mx);
    float corr = exp2f(m_run - mnew);
    m_run = mnew;
    float pr[4][4]; float rs = 0.0f;
#pragma unroll
    for (int mt = 0; mt < 4; ++mt)
#pragma unroll
      for (int r = 0; r < 4; ++r) { float e = exp2f(st[mt][r] - mnew); pr[mt][r] = e; rs += e; }
    rs += __shfl_xor(rs, 16);
    rs += __shfl_xor(rs, 32);
    l_run = l_run * corr + rs;
#pragma unroll
    for (int r = 0; r < 4; ++r) {
      float c = __shfl(corr, (lane & 48) + lg * 4 + r);
#pragma unroll
      for (int dt = 0; dt < 8; ++dt) oacc[dt][r] *= c;
    }
    short8 pf2[2];
#pragma unroll
    for (int c = 0; c < 2; ++c) {
      short8 v;
      v[0]=f2bf(pr[2*c][0]); v[1]=f2bf(pr[2*c][1]); v[2]=f2bf(pr[2*c][2]); v[3]=f2bf(pr[2*c][3]);
      v[4]=f2bf(pr[2*c+1][0]); v[5]=f2bf(pr[2*c+1][1]); v[6]=f2bf(pr[2*c+1][2]); v[7]=f2bf(pr[2*c+1][3]);
      pf2[c] = v;
    }
#pragma unroll
    for (int dt = 0; dt < 8; ++dt) {
      int rowb = (dt * 16 + lr) * 136;
#pragma unroll
      for (int c = 0; c < 2; ++c) {
        FragU b;
        b.h[0] = *(short4*)((char*)Vt + rowb + c*64      + lg*8);
        b.h[1] = *(short4*)((char*)Vt + rowb + c*64 + 32 + lg*8);
        oacc[dt] = __builtin_amdgcn_mfma_f32_16x16x32_bf16(pf2[c], b.v, oacc[dt], 0, 0, 0);
      }
    }
  }
#pragma unroll
  for (int r = 0; r < 4; ++r) {
    float li = __shfl(l_run, (lane & 48) + lg * 4 + r);
    float inv = 1.0f / li;
    float* orow = Op + (size_t)(q0w + lg * 4 + r) * Dc;
#pragma unroll
    for (int dt = 0; dt < 8; ++dt) orow[dt * 16 + lr] = oacc[dt][r] * inv;
  }
}

} // namespace

extern "C" void kernel_launch(void* const* d_in, const int* in_sizes, int n_in,
                              void* d_out, int out_size, void* d_ws, size_t ws_size,
                              hipStream_t stream) {
  const float* Q = (const float*)d_in[0];
  const float* K = (const float*)d_in[1];
  const float* V = (const float*)d_in[2];
  float* O = (float*)d_out;
  // ws: Kw (16.8MB) | Vw (16.8MB) | Opart 2x16.8MB fp32 | Mbuf 256KB | Lbuf 256KB
  const size_t need = 2 * ELEMS * sizeof(short) + ELEMS * sizeof(float)
                    + 2 * MLROWS * sizeof(float);
  if (ws_size >= need) {
    short* Kw = (short*)d_ws;
    short* Vw = Kw + ELEMS;
    float* Opart = (float*)(Vw + ELEMS);
    float* Mbuf  = Opart + ELEMS;             // 2*256*128*128 == ELEMS floats
    float* Lbuf  = Mbuf + MLROWS;
    conv_kv<<<dim3(4096 + 1024), dim3(256), 0, stream>>>(K, V, Kw, Vw);
    attn_fwd11<<<dim3(768), dim3(256), 0, stream>>>(Q, Kw, Vw, O, Opart, Mbuf, Lbuf);
    combine<<<dim3(4096), dim3(256), 0, stream>>>(Opart, Mbuf, Lbuf, O);
  } else {
    attn_fb<<<dim3(BH * NKT), dim3(256), 0, stream>>>(Q, K, V, O);
  }
}

// Round 12
// 88.542 us; speedup vs baseline: 1.1126x; 1.1126x over previous
//
#include <hip/hip_runtime.h>
#include <hip/hip_bf16.h>

namespace {

constexpr int Bc = 2, Hc = 16, Lc = 2048, Dc = 128;
constexpr int KVBLK = 64;
constexpr int BH  = Bc * Hc;      // 32
constexpr int NKT = Lc / KVBLK;   // 32
constexpr int QB  = 128;          // q rows per block
constexpr int NQT = Lc / QB;      // 16
// 1/sqrt(128) * log2(e)  (softmax in exp2 domain)
constexpr float SCALE = 0.08838834764831845f * 1.4426950408889634f;

using f32x4   = __attribute__((ext_vector_type(4))) float;
using f32x16  = __attribute__((ext_vector_type(16))) float;
using short8  = __attribute__((ext_vector_type(8))) short;

union FragU { short8 v; short4 h[2]; };
union PFU  { short8 v; unsigned u[4]; };

__device__ inline short f2bf(float f) {
  unsigned u = __builtin_bit_cast(unsigned, f);
  u += 0x7fffu + ((u >> 16) & 1u);          // RNE
  return (short)(u >> 16);
}

__device__ inline unsigned cvtpk(float a, float b) {
  __hip_bfloat162 h = __float22bfloat162_rn(float2{a, b});
  unsigned r;
  __builtin_memcpy(&r, &h, 4);
  return r;
}

__device__ inline void gload_lds16(const short* g, short* l) {
  __builtin_amdgcn_global_load_lds(
      (const __attribute__((address_space(1))) void*)g,
      (__attribute__((address_space(3))) void*)l, 16, 0, 0);
}

// ======== fused pre-pass: K and V fp32 -> bf16 in FRAGMENT-ORDERED tiles ========
// K tile (16 KB): granule g = (ks*2+s)*64 + lane holds bf16 of
// K[row=s*32+ln][k = ks*16 + hi*4 + {0..3, 8..11}] (one 32x32x16 A-fragment/lane).
// V tile: granule g = (nt*4+kc)*64 + lane -> V^T fragment d=nt*32+ln,
// kv = kc*16 + hi*4 + {0..3, 8..11}.  (correctness-proven R6-R11)
__global__ __launch_bounds__(256) void conv_kv(const float* __restrict__ Kg,
                                               const float* __restrict__ Vg,
                                               short* __restrict__ Kw,
                                               short* __restrict__ Vw) {
  __shared__ short Vs[64 * 130];
  const int b = blockIdx.x;
  if (b < 4096) {
    int tid  = b * 256 + threadIdx.x;
    int rem  = tid & 1023;
    int tb   = tid >> 10;
    int ks   = rem >> 7;
    int s    = (rem >> 6) & 1;
    int lane = rem & 63;
    int hi   = lane >> 5, ln = lane & 31;
    const float* src = Kg + ((size_t)tb * 64 + s * 32 + ln) * 128 + ks * 16 + hi * 4;
    float4 a = *(const float4*)src;
    float4 c = *(const float4*)(src + 8);
    short8 v;
    v[0] = f2bf(a.x); v[1] = f2bf(a.y); v[2] = f2bf(a.z); v[3] = f2bf(a.w);
    v[4] = f2bf(c.x); v[5] = f2bf(c.y); v[6] = f2bf(c.z); v[7] = f2bf(c.w);
    *(short8*)(Kw + (size_t)tb * 8192 + rem * 8) = v;
  } else {
    int tb  = b - 4096;
    int tid = threadIdx.x;
    const float* vt = Vg + (size_t)tb * 8192;
#pragma unroll
    for (int p = 0; p < 8; ++p) {
      int g  = p * 256 + tid;
      int kv = g >> 5;
      int c4 = g & 31;
      float4 v = *((const float4*)vt + g);
      short* d = &Vs[kv * 130 + c4 * 4];
      d[0] = f2bf(v.x); d[1] = f2bf(v.y); d[2] = f2bf(v.z); d[3] = f2bf(v.w);
    }
    __syncthreads();
#pragma unroll
    for (int p = 0; p < 4; ++p) {
      int g    = p * 256 + tid;
      int nt   = g >> 8;
      int kc   = (g >> 6) & 3;
      int lane = g & 63;
      int hi   = lane >> 5, ln = lane & 31;
      int d    = nt * 32 + ln;
      int k0   = kc * 16 + hi * 4;
      short8 o;
#pragma unroll
      for (int j = 0; j < 4; ++j) o[j]     = Vs[(k0 + j)     * 130 + d];
#pragma unroll
      for (int j = 0; j < 4; ++j) o[4 + j] = Vs[(k0 + 8 + j) * 130 + d];
      *(short8*)(Vw + (size_t)tb * 8192 + g * 8) = o;
    }
  }
}

// ====== main attention: R8 skeleton, minimal cross-lane (single rescale,
//        deferred l-reduction, no sched pin, one PV cluster) ======
__global__ __launch_bounds__(256, 2) void attn_fwd12(
    const float* __restrict__ Qg, const short* __restrict__ Kw,
    const short* __restrict__ Vw, float* __restrict__ Og) {

  __shared__ __align__(16) short lds[2][2][8192];   // 64 KB -> 2 blocks/CU

  const int tid  = threadIdx.x;
  const int wave = tid >> 6;
  const int lane = tid & 63;
  const int hi   = lane >> 5;
  const int ln   = lane & 31;

  const int bid = blockIdx.x;
  const int bh  = bid & (BH - 1);             // bid%8 == bh%8 -> head-per-XCD L2 affinity
  const int r5  = bid >> 5;
  const int qt  = (bid < 256) ? (NQT - 1 - r5) : (r5 - 8);   // anti-correlated CU load
  const int q0w = qt * QB + wave * 32;

  const float* Qp  = Qg + (size_t)bh * Lc * Dc;
  float*       Op  = Og + (size_t)bh * Lc * Dc;
  const short* Kwp = Kw + (size_t)bh * NKT * 8192;
  const short* Vwp = Vw + (size_t)bh * NKT * 8192;

  // ---- preload Q fragments (B-operand), pre-scaled ----
  short8 qf[8];
  {
    const float* qrow = Qp + (size_t)(q0w + ln) * Dc + hi * 4;
#pragma unroll
    for (int ks = 0; ks < 8; ++ks) {
      float4 a = *(const float4*)(qrow + ks * 16);
      float4 b = *(const float4*)(qrow + ks * 16 + 8);
      short8 v;
      v[0] = f2bf(a.x * SCALE); v[1] = f2bf(a.y * SCALE);
      v[2] = f2bf(a.z * SCALE); v[3] = f2bf(a.w * SCALE);
      v[4] = f2bf(b.x * SCALE); v[5] = f2bf(b.y * SCALE);
      v[6] = f2bf(b.z * SCALE); v[7] = f2bf(b.w * SCALE);
      qf[ks] = v;
    }
  }

  float m_run = -1e30f;
  float l_run = 0.0f;                         // PARTIAL: this lane's 32 kv slots only
  f32x16 oacc[4];
#pragma unroll
  for (int nt = 0; nt < 4; ++nt)
#pragma unroll
    for (int r = 0; r < 16; ++r) oacc[nt][r] = 0.0f;

  const int ntiles = 2 * (qt + 1);

  auto stage = [&](int t, int b) {
    const short* gk = Kwp + (size_t)t * 8192 + tid * 8;
    const short* gv = Vwp + (size_t)t * 8192 + tid * 8;
    short* lk = &lds[b][0][tid * 8];
    short* lv = &lds[b][1][tid * 8];
#pragma unroll
    for (int i = 0; i < 4; ++i) gload_lds16(gk + i * 2048, lk + i * 2048);
#pragma unroll
    for (int i = 0; i < 4; ++i) gload_lds16(gv + i * 2048, lv + i * 2048);
  };

  stage(0, 0);

  for (int t = 0; t < ntiles; ++t) {
    const int cur = t & 1;
    __builtin_amdgcn_s_barrier();             // buf[cur^1] free
    if (t + 1 < ntiles) {
      stage(t + 1, cur ^ 1);
      asm volatile("s_waitcnt vmcnt(8)" ::: "memory");   // tile t landed (counted)
    } else {
      asm volatile("s_waitcnt vmcnt(0)" ::: "memory");
    }
    __builtin_amdgcn_s_barrier();             // tile t visible to all waves

    const int kv0 = t * KVBLK;
    if (q0w + 31 < kv0) continue;             // fully-masked wave: stage-only

    const short* Kl = &lds[cur][0][lane * 8];
    const short* Vl = &lds[cur][1][lane * 8];

    // ---- QK(t): S^T = K*Q^T. col=q=ln, kv row=(r&3)+8*(r>>2)+4*hi (+32 for s1) ----
    f32x16 s0, s1;
#pragma unroll
    for (int r = 0; r < 16; ++r) { s0[r] = 0.0f; s1[r] = 0.0f; }
    __builtin_amdgcn_s_setprio(1);
#pragma unroll
    for (int ks = 0; ks < 8; ++ks)
      s0 = __builtin_amdgcn_mfma_f32_32x32x16_bf16(
          *(const short8*)(Kl + ks * 1024), qf[ks], s0, 0, 0, 0);
#pragma unroll
    for (int ks = 0; ks < 8; ++ks)
      s1 = __builtin_amdgcn_mfma_f32_32x32x16_bf16(
          *(const short8*)(Kl + ks * 1024 + 512), qf[ks], s1, 0, 0, 0);
    __builtin_amdgcn_s_setprio(0);

    // ---- causal mask (diagonal-overlap tiles only) ----
    if (kv0 + 63 > q0w) {
      const int qg = q0w + ln;
#pragma unroll
      for (int r = 0; r < 16; ++r) {
        int kvr = kv0 + (r & 3) + 8 * (r >> 2) + 4 * hi;
        if (kvr > qg)      s0[r] = -1e30f;
        if (kvr + 32 > qg) s1[r] = -1e30f;
      }
    }

    // ---- single per-tile max + defer-max rescale (ONE shfl per tile) ----
    float ma = s0[0], mb = s0[8], mc = s1[0], md = s1[8];
#pragma unroll
    for (int r = 1; r < 8; ++r) {
      ma = fmaxf(ma, s0[r]); mb = fmaxf(mb, s0[8 + r]);
      mc = fmaxf(mc, s1[r]); md = fmaxf(md, s1[8 + r]);
    }
    float mx = fmaxf(fmaxf(ma, mb), fmaxf(mc, md));
    mx = fmaxf(mx, __shfl_xor(mx, 32));

    if (!__all(mx - m_run <= 8.0f)) {         // rescale path (rare, THR=8)
      float mnew = fmaxf(m_run, mx);
      float corr = exp2f(m_run - mnew);
      m_run = mnew;
      l_run *= corr;                          // partial scaled uniformly (corr row-wide)
#pragma unroll
      for (int r = 0; r < 16; ++r) {
        int qrow = (r & 3) + 8 * (r >> 2) + 4 * hi;
        float c = __shfl(corr, qrow);
#pragma unroll
        for (int nt = 0; nt < 4; ++nt) oacc[nt][r] *= c;
      }
    }

    // ---- P = exp2(S - m), packed via cvt_pk; l accumulates LANE-PARTIAL (no shfl) ----
    PFU pf0, pf1, pf2, pf3;
    float rsa = 0.f, rsb = 0.f, rsc = 0.f, rsd = 0.f;
#pragma unroll
    for (int e2 = 0; e2 < 4; ++e2) {
      float p00 = exp2f(s0[2 * e2]         - m_run);
      float p01 = exp2f(s0[2 * e2 + 1]     - m_run);
      float p10 = exp2f(s0[8 + 2 * e2]     - m_run);
      float p11 = exp2f(s0[8 + 2 * e2 + 1] - m_run);
      float p20 = exp2f(s1[2 * e2]         - m_run);
      float p21 = exp2f(s1[2 * e2 + 1]     - m_run);
      float p30 = exp2f(s1[8 + 2 * e2]     - m_run);
      float p31 = exp2f(s1[8 + 2 * e2 + 1] - m_run);
      rsa += p00 + p01;  rsb += p10 + p11;
      rsc += p20 + p21;  rsd += p30 + p31;
      pf0.u[e2] = cvtpk(p00, p01);
      pf1.u[e2] = cvtpk(p10, p11);
      pf2.u[e2] = cvtpk(p20, p21);
      pf3.u[e2] = cvtpk(p30, p31);
    }
    l_run += (rsa + rsb) + (rsc + rsd);

    // ---- O += P * V : one 16-MFMA cluster ----
    __builtin_amdgcn_s_setprio(1);
#pragma unroll
    for (int nt = 0; nt < 4; ++nt) {
      oacc[nt] = __builtin_amdgcn_mfma_f32_32x32x16_bf16(
          pf0.v, *(const short8*)(Vl + (nt * 4 + 0) * 512), oacc[nt], 0, 0, 0);
      oacc[nt] = __builtin_amdgcn_mfma_f32_32x32x16_bf16(
          pf1.v, *(const short8*)(Vl + (nt * 4 + 1) * 512), oacc[nt], 0, 0, 0);
      oacc[nt] = __builtin_amdgcn_mfma_f32_32x32x16_bf16(
          pf2.v, *(const short8*)(Vl + (nt * 4 + 2) * 512), oacc[nt], 0, 0, 0);
      oacc[nt] = __builtin_amdgcn_mfma_f32_32x32x16_bf16(
          pf3.v, *(const short8*)(Vl + (nt * 4 + 3) * 512), oacc[nt], 0, 0, 0);
    }
    __builtin_amdgcn_s_setprio(0);
  }

  // ---- epilogue: reduce l across hi halves ONCE; O row q=(r&3)+8*(r>>2)+4*hi ----
  float l_tot = l_run + __shfl_xor(l_run, 32);
  float linv  = 1.0f / l_tot;
#pragma unroll
  for (int r = 0; r < 16; ++r) {
    int qrow = (r & 3) + 8 * (r >> 2) + 4 * hi;
    float il = __shfl(linv, qrow);
    float* orow = Op + (size_t)(q0w + qrow) * Dc + ln;
#pragma unroll
    for (int nt = 0; nt < 4; ++nt)
      orow[nt * 32] = oacc[nt][r] * il;
  }
}

// ===================== fallback (ws too small): R1 kernel =====================
__device__ inline unsigned packbf(float a, float b) {
  return (unsigned)(unsigned short)f2bf(a) | ((unsigned)(unsigned short)f2bf(b) << 16);
}

__global__ __launch_bounds__(256, 2) void attn_fb(
    const float* __restrict__ Qg, const float* __restrict__ Kg,
    const float* __restrict__ Vg, float* __restrict__ Og) {
  __shared__ __align__(16) short Klds[KVBLK * Dc];
  __shared__ __align__(16) short Vt[Dc * 68];
  const int tid = threadIdx.x, wave = tid >> 6, lane = tid & 63;
  const int lg = lane >> 4, lr = lane & 15;
  const int bid = blockIdx.x;
  const int bh = bid & (BH - 1);
  const int qt = 31 - (bid >> 5);
  const int q0w = qt * 64 + wave * 16;
  const float* Qp = Qg + (size_t)bh * Lc * Dc;
  const float* Kp = Kg + (size_t)bh * Lc * Dc;
  const float* Vp = Vg + (size_t)bh * Lc * Dc;
  float* Op = Og + (size_t)bh * Lc * Dc;
  short8 qf[4];
  {
    const float* qrow = Qp + (size_t)(q0w + lr) * Dc;
#pragma unroll
    for (int dc = 0; dc < 4; ++dc) {
      float4 a = *(const float4*)(qrow + dc * 32 + lg * 4);
      float4 b = *(const float4*)(qrow + dc * 32 + 16 + lg * 4);
      short8 v;
      v[0]=f2bf(a.x*SCALE); v[1]=f2bf(a.y*SCALE); v[2]=f2bf(a.z*SCALE); v[3]=f2bf(a.w*SCALE);
      v[4]=f2bf(b.x*SCALE); v[5]=f2bf(b.y*SCALE); v[6]=f2bf(b.z*SCALE); v[7]=f2bf(b.w*SCALE);
      qf[dc] = v;
    }
  }
  const f32x4 zero4 = {0.f,0.f,0.f,0.f};
  float m_run = -1e30f, l_run = 0.0f;
  f32x4 oacc[8];
#pragma unroll
  for (int dt = 0; dt < 8; ++dt) oacc[dt] = zero4;
  const int ntiles = qt + 1, c4 = tid & 31, rK = tid >> 5;
  for (int t = 0; t < ntiles; ++t) {
    const int kv0 = t * KVBLK;
    __syncthreads();
#pragma unroll
    for (int p = 0; p < 8; ++p) {
      int row = rK + p * 8;
      float4 k4 = *(const float4*)(Kp + (size_t)(kv0 + row) * Dc + c4 * 4);
      short4 pk; pk.x=f2bf(k4.x); pk.y=f2bf(k4.y); pk.z=f2bf(k4.z); pk.w=f2bf(k4.w);
      *(short4*)((char*)Klds + row * 256 + ((c4 * 8) ^ ((row & 7) << 4))) = pk;
    }
#pragma unroll
    for (int p = 0; p < 4; ++p) {
      int r0 = rK * 2 + p * 16;
      float4 v0 = *(const float4*)(Vp + (size_t)(kv0 + r0) * Dc + c4 * 4);
      float4 v1 = *(const float4*)(Vp + (size_t)(kv0 + r0 + 1) * Dc + c4 * 4);
      char* vb2 = (char*)Vt + r0 * 2;
      *(unsigned*)(vb2 + (c4*4+0)*136) = packbf(v0.x, v1.x);
      *(unsigned*)(vb2 + (c4*4+1)*136) = packbf(v0.y, v1.y);
      *(unsigned*)(vb2 + (c4*4+2)*136) = packbf(v0.z, v1.z);
      *(unsigned*)(vb2 + (c4*4+3)*136) = packbf(v0.w, v1.w);
    }
    __syncthreads();
    f32x4 st[4];
#pragma unroll
    for (int mt = 0; mt < 4; ++mt) st[mt] = zero4;
#pragma unroll
    for (int dc = 0; dc < 4; ++dc)
#pragma unroll
      for (int mt = 0; mt < 4; ++mt) {
        int row = mt * 16 + lr, sw2 = (row & 7) << 4;
        FragU a;
        a.h[0] = *(short4*)((char*)Klds + row*256 + ((dc*64      + lg*8) ^ sw2));
        a.h[1] = *(short4*)((char*)Klds + row*256 + ((dc*64 + 32 + lg*8) ^ sw2));
        st[mt] = __builtin_amdgcn_mfma_f32_16x16x32_bf16(a.v, qf[dc], st[mt], 0, 0, 0);
      }
    if (t == ntiles - 1) {
      const int qg = q0w + lr;
#pragma unroll
      for (int mt = 0; mt < 4; ++mt)
#pragma unroll
        for (int r = 0; r < 4; ++r)
          if (kv0 + mt * 16 + lg * 4 + r > qg) st[mt][r] = -1e30f;
    }
    float mx = st[0][0];
#pragma unroll
    for (int mt = 0; mt < 4; ++mt)
#pragma unroll
      for (int r = 0; r < 4; ++r) mx = fmaxf(mx, st[mt][r]);
    mx = fmaxf(mx, __shfl_xor(mx, 16));
    mx = fmaxf(mx, __shfl_xor(mx, 32));
    float mnew = fmaxf(m_run, mx);
    float corr = exp2f(m_run - mnew);
    m_run = mnew;
    float pr[4][4]; float rs = 0.0f;
#pragma unroll
    for (int mt = 0; mt < 4; ++mt)
#pragma unroll
      for (int r = 0; r < 4; ++r) { float e = exp2f(st[mt][r] - mnew); pr[mt][r] = e; rs += e; }
    rs += __shfl_xor(rs, 16);
    rs += __shfl_xor(rs, 32);
    l_run = l_run * corr + rs;
#pragma unroll
    for (int r = 0; r < 4; ++r) {
      float c = __shfl(corr, (lane & 48) + lg * 4 + r);
#pragma unroll
      for (int dt = 0; dt < 8; ++dt) oacc[dt][r] *= c;
    }
    short8 pf2[2];
#pragma unroll
    for (int c = 0; c < 2; ++c) {
      short8 v;
      v[0]=f2bf(pr[2*c][0]); v[1]=f2bf(pr[2*c][1]); v[2]=f2bf(pr[2*c][2]); v[3]=f2bf(pr[2*c][3]);
      v[4]=f2bf(pr[2*c+1][0]); v[5]=f2bf(pr[2*c+1][1]); v[6]=f2bf(pr[2*c+1][2]); v[7]=f2bf(pr[2*c+1][3]);
      pf2[c] = v;
    }
#pragma unroll
    for (int dt = 0; dt < 8; ++dt) {
      int rowb = (dt * 16 + lr) * 136;
#pragma unroll
      for (int c = 0; c < 2; ++c) {
        FragU b;
        b.h[0] = *(short4*)((char*)Vt + rowb + c*64      + lg*8);
        b.h[1] = *(short4*)((char*)Vt + rowb + c*64 + 32 + lg*8);
        oacc[dt] = __builtin_amdgcn_mfma_f32_16x16x32_bf16(pf2[c], b.v, oacc[dt], 0, 0, 0);
      }
    }
  }
#pragma unroll
  for (int r = 0; r < 4; ++r) {
    float li = __shfl(l_run, (lane & 48) + lg * 4 + r);
    float inv = 1.0f / li;
    float* orow = Op + (size_t)(q0w + lg * 4 + r) * Dc;
#pragma unroll
    for (int dt = 0; dt < 8; ++dt) orow[dt * 16 + lr] = oacc[dt][r] * inv;
  }
}

} // namespace

extern "C" void kernel_launch(void* const* d_in, const int* in_sizes, int n_in,
                              void* d_out, int out_size, void* d_ws, size_t ws_size,
                              hipStream_t stream) {
  const float* Q = (const float*)d_in[0];
  const float* K = (const float*)d_in[1];
  const float* V = (const float*)d_in[2];
  float* O = (float*)d_out;
  const size_t elems = (size_t)BH * Lc * Dc;          // 8.39M per tensor
  const size_t need  = 2 * elems * sizeof(short);     // 33.5 MB
  if (ws_size >= need) {
    short* Kw = (short*)d_ws;
    short* Vw = Kw + elems;
    conv_kv<<<dim3(4096 + 1024), dim3(256), 0, stream>>>(K, V, Kw, Vw);
    attn_fwd12<<<dim3(BH * NQT), dim3(256), 0, stream>>>(Q, Kw, Vw, O);
  } else {
    attn_fb<<<dim3(BH * NKT), dim3(256), 0, stream>>>(Q, K, V, O);
  }
}

// Round 13
// 86.608 us; speedup vs baseline: 1.1375x; 1.0223x over previous
//
#include <hip/hip_runtime.h>
#include <hip/hip_bf16.h>

namespace {

constexpr int Bc = 2, Hc = 16, Lc = 2048, Dc = 128;
constexpr int KVBLK = 64;
constexpr int BH  = Bc * Hc;      // 32
constexpr int NKT = Lc / KVBLK;   // 32
constexpr int QB  = 128;          // q rows per block
constexpr int NQT = Lc / QB;      // 16
// 1/sqrt(128) * log2(e)  (softmax in exp2 domain)
constexpr float SCALE = 0.08838834764831845f * 1.4426950408889634f;

using f32x4   = __attribute__((ext_vector_type(4))) float;
using f32x16  = __attribute__((ext_vector_type(16))) float;
using short8  = __attribute__((ext_vector_type(8))) short;

union FragU { short8 v; short4 h[2]; };
union PFU  { short8 v; unsigned u[4]; };

__device__ inline short f2bf(float f) {
  unsigned u = __builtin_bit_cast(unsigned, f);
  u += 0x7fffu + ((u >> 16) & 1u);          // RNE
  return (short)(u >> 16);
}

__device__ inline unsigned cvtpk(float a, float b) {
  __hip_bfloat162 h = __float22bfloat162_rn(float2{a, b});
  unsigned r;
  __builtin_memcpy(&r, &h, 4);
  return r;
}

__device__ inline void gload_lds16(const short* g, short* l) {
  __builtin_amdgcn_global_load_lds(
      (const __attribute__((address_space(1))) void*)g,
      (__attribute__((address_space(3))) void*)l, 16, 0, 0);
}

// ======== fused pre-pass: K and V fp32 -> bf16 in FRAGMENT-ORDERED tiles ========
// K tile (16 KB): granule g = (ks*2+s)*64 + lane holds bf16 of
// K[row=s*32+ln][k = ks*16 + hi*4 + {0..3, 8..11}] (one 32x32x16 A-fragment/lane).
// V tile: granule g = (nt*4+kc)*64 + lane -> V^T fragment d=nt*32+ln,
// kv = kc*16 + hi*4 + {0..3, 8..11}.  (correctness-proven R6-R12)
__global__ __launch_bounds__(256) void conv_kv(const float* __restrict__ Kg,
                                               const float* __restrict__ Vg,
                                               short* __restrict__ Kw,
                                               short* __restrict__ Vw) {
  __shared__ short Vs[64 * 130];
  const int b = blockIdx.x;
  if (b < 4096) {
    int tid  = b * 256 + threadIdx.x;
    int rem  = tid & 1023;
    int tb   = tid >> 10;
    int ks   = rem >> 7;
    int s    = (rem >> 6) & 1;
    int lane = rem & 63;
    int hi   = lane >> 5, ln = lane & 31;
    const float* src = Kg + ((size_t)tb * 64 + s * 32 + ln) * 128 + ks * 16 + hi * 4;
    float4 a = *(const float4*)src;
    float4 c = *(const float4*)(src + 8);
    short8 v;
    v[0] = f2bf(a.x); v[1] = f2bf(a.y); v[2] = f2bf(a.z); v[3] = f2bf(a.w);
    v[4] = f2bf(c.x); v[5] = f2bf(c.y); v[6] = f2bf(c.z); v[7] = f2bf(c.w);
    *(short8*)(Kw + (size_t)tb * 8192 + rem * 8) = v;
  } else {
    int tb  = b - 4096;
    int tid = threadIdx.x;
    const float* vt = Vg + (size_t)tb * 8192;
#pragma unroll
    for (int p = 0; p < 8; ++p) {
      int g  = p * 256 + tid;
      int kv = g >> 5;
      int c4 = g & 31;
      float4 v = *((const float4*)vt + g);
      short* d = &Vs[kv * 130 + c4 * 4];
      d[0] = f2bf(v.x); d[1] = f2bf(v.y); d[2] = f2bf(v.z); d[3] = f2bf(v.w);
    }
    __syncthreads();
#pragma unroll
    for (int p = 0; p < 4; ++p) {
      int g    = p * 256 + tid;
      int nt   = g >> 8;
      int kc   = (g >> 6) & 3;
      int lane = g & 63;
      int hi   = lane >> 5, ln = lane & 31;
      int d    = nt * 32 + ln;
      int k0   = kc * 16 + hi * 4;
      short8 o;
#pragma unroll
      for (int j = 0; j < 4; ++j) o[j]     = Vs[(k0 + j)     * 130 + d];
#pragma unroll
      for (int j = 0; j < 4; ++j) o[4 + j] = Vs[(k0 + 8 + j) * 130 + d];
      *(short8*)(Vw + (size_t)tb * 8192 + g * 8) = o;
    }
  }
}

// ====== main attention: R12 skeleton + split-accumulate QK (4 chains of 4) ======
__global__ __launch_bounds__(256, 2) void attn_fwd13(
    const float* __restrict__ Qg, const short* __restrict__ Kw,
    const short* __restrict__ Vw, float* __restrict__ Og) {

  __shared__ __align__(16) short lds[2][2][8192];   // 64 KB -> 2 blocks/CU

  const int tid  = threadIdx.x;
  const int wave = tid >> 6;
  const int lane = tid & 63;
  const int hi   = lane >> 5;
  const int ln   = lane & 31;

  const int bid = blockIdx.x;
  const int bh  = bid & (BH - 1);             // bid%8 == bh%8 -> head-per-XCD L2 affinity
  const int r5  = bid >> 5;
  const int qt  = (bid < 256) ? (NQT - 1 - r5) : (r5 - 8);   // anti-correlated CU load
  const int q0w = qt * QB + wave * 32;

  const float* Qp  = Qg + (size_t)bh * Lc * Dc;
  float*       Op  = Og + (size_t)bh * Lc * Dc;
  const short* Kwp = Kw + (size_t)bh * NKT * 8192;
  const short* Vwp = Vw + (size_t)bh * NKT * 8192;

  // ---- preload Q fragments (B-operand), pre-scaled ----
  short8 qf[8];
  {
    const float* qrow = Qp + (size_t)(q0w + ln) * Dc + hi * 4;
#pragma unroll
    for (int ks = 0; ks < 8; ++ks) {
      float4 a = *(const float4*)(qrow + ks * 16);
      float4 b = *(const float4*)(qrow + ks * 16 + 8);
      short8 v;
      v[0] = f2bf(a.x * SCALE); v[1] = f2bf(a.y * SCALE);
      v[2] = f2bf(a.z * SCALE); v[3] = f2bf(a.w * SCALE);
      v[4] = f2bf(b.x * SCALE); v[5] = f2bf(b.y * SCALE);
      v[6] = f2bf(b.z * SCALE); v[7] = f2bf(b.w * SCALE);
      qf[ks] = v;
    }
  }

  float m_run = -1e30f;
  float l_run = 0.0f;                         // lane-partial (32 kv slots); reduced once
  f32x16 oacc[4];
#pragma unroll
  for (int nt = 0; nt < 4; ++nt)
#pragma unroll
    for (int r = 0; r < 16; ++r) oacc[nt][r] = 0.0f;

  const int ntiles = 2 * (qt + 1);

  auto stage = [&](int t, int b) {
    const short* gk = Kwp + (size_t)t * 8192 + tid * 8;
    const short* gv = Vwp + (size_t)t * 8192 + tid * 8;
    short* lk = &lds[b][0][tid * 8];
    short* lv = &lds[b][1][tid * 8];
#pragma unroll
    for (int i = 0; i < 4; ++i) gload_lds16(gk + i * 2048, lk + i * 2048);
#pragma unroll
    for (int i = 0; i < 4; ++i) gload_lds16(gv + i * 2048, lv + i * 2048);
  };

  stage(0, 0);

  for (int t = 0; t < ntiles; ++t) {
    const int cur = t & 1;
    __builtin_amdgcn_s_barrier();             // buf[cur^1] free
    if (t + 1 < ntiles) {
      stage(t + 1, cur ^ 1);
      asm volatile("s_waitcnt vmcnt(8)" ::: "memory");   // tile t landed (counted)
    } else {
      asm volatile("s_waitcnt vmcnt(0)" ::: "memory");
    }
    __builtin_amdgcn_s_barrier();             // tile t visible to all waves

    const int kv0 = t * KVBLK;
    if (q0w + 31 < kv0) continue;             // fully-masked wave: stage-only

    const short* Kl = &lds[cur][0][lane * 8];
    const short* Vl = &lds[cur][1][lane * 8];

    // ---- QK(t): split-accumulate -> 4 independent chains of depth 4 ----
    f32x16 s0a, s0b, s1a, s1b;
#pragma unroll
    for (int r = 0; r < 16; ++r) { s0a[r] = 0.0f; s0b[r] = 0.0f; s1a[r] = 0.0f; s1b[r] = 0.0f; }
    __builtin_amdgcn_s_setprio(1);
#pragma unroll
    for (int ks = 0; ks < 4; ++ks) {
      s0a = __builtin_amdgcn_mfma_f32_32x32x16_bf16(
          *(const short8*)(Kl + ks * 1024), qf[ks], s0a, 0, 0, 0);
      s0b = __builtin_amdgcn_mfma_f32_32x32x16_bf16(
          *(const short8*)(Kl + (ks + 4) * 1024), qf[ks + 4], s0b, 0, 0, 0);
      s1a = __builtin_amdgcn_mfma_f32_32x32x16_bf16(
          *(const short8*)(Kl + ks * 1024 + 512), qf[ks], s1a, 0, 0, 0);
      s1b = __builtin_amdgcn_mfma_f32_32x32x16_bf16(
          *(const short8*)(Kl + (ks + 4) * 1024 + 512), qf[ks + 4], s1b, 0, 0, 0);
    }
    __builtin_amdgcn_s_setprio(0);
    f32x16 s0 = s0a + s0b;
    f32x16 s1 = s1a + s1b;

    // ---- causal mask (diagonal-overlap tiles only) ----
    if (kv0 + 63 > q0w) {
      const int qg = q0w + ln;
#pragma unroll
      for (int r = 0; r < 16; ++r) {
        int kvr = kv0 + (r & 3) + 8 * (r >> 2) + 4 * hi;
        if (kvr > qg)      s0[r] = -1e30f;
        if (kvr + 32 > qg) s1[r] = -1e30f;
      }
    }

    // ---- single per-tile max + defer-max rescale (ONE shfl per tile) ----
    float ma = s0[0], mb = s0[8], mc = s1[0], md = s1[8];
#pragma unroll
    for (int r = 1; r < 8; ++r) {
      ma = fmaxf(ma, s0[r]); mb = fmaxf(mb, s0[8 + r]);
      mc = fmaxf(mc, s1[r]); md = fmaxf(md, s1[8 + r]);
    }
    float mx = fmaxf(fmaxf(ma, mb), fmaxf(mc, md));
    mx = fmaxf(mx, __shfl_xor(mx, 32));

    if (!__all(mx - m_run <= 8.0f)) {         // rescale path (rare, THR=8)
      float mnew = fmaxf(m_run, mx);
      float corr = exp2f(m_run - mnew);
      m_run = mnew;
      l_run *= corr;
#pragma unroll
      for (int r = 0; r < 16; ++r) {
        int qrow = (r & 3) + 8 * (r >> 2) + 4 * hi;
        float c = __shfl(corr, qrow);
#pragma unroll
        for (int nt = 0; nt < 4; ++nt) oacc[nt][r] *= c;
      }
    }

    // ---- P = exp2(S - m), packed via cvt_pk; l stays lane-partial (no shfl) ----
    PFU pf0, pf1, pf2, pf3;
    float rsa = 0.f, rsb = 0.f, rsc = 0.f, rsd = 0.f;
#pragma unroll
    for (int e2 = 0; e2 < 4; ++e2) {
      float p00 = exp2f(s0[2 * e2]         - m_run);
      float p01 = exp2f(s0[2 * e2 + 1]     - m_run);
      float p10 = exp2f(s0[8 + 2 * e2]     - m_run);
      float p11 = exp2f(s0[8 + 2 * e2 + 1] - m_run);
      float p20 = exp2f(s1[2 * e2]         - m_run);
      float p21 = exp2f(s1[2 * e2 + 1]     - m_run);
      float p30 = exp2f(s1[8 + 2 * e2]     - m_run);
      float p31 = exp2f(s1[8 + 2 * e2 + 1] - m_run);
      rsa += p00 + p01;  rsb += p10 + p11;
      rsc += p20 + p21;  rsd += p30 + p31;
      pf0.u[e2] = cvtpk(p00, p01);
      pf1.u[e2] = cvtpk(p10, p11);
      pf2.u[e2] = cvtpk(p20, p21);
      pf3.u[e2] = cvtpk(p30, p31);
    }
    l_run += (rsa + rsb) + (rsc + rsd);

    // ---- O += P * V : one 16-MFMA cluster (4 independent chains of 4) ----
    __builtin_amdgcn_s_setprio(1);
#pragma unroll
    for (int nt = 0; nt < 4; ++nt) {
      oacc[nt] = __builtin_amdgcn_mfma_f32_32x32x16_bf16(
          pf0.v, *(const short8*)(Vl + (nt * 4 + 0) * 512), oacc[nt], 0, 0, 0);
      oacc[nt] = __builtin_amdgcn_mfma_f32_32x32x16_bf16(
          pf1.v, *(const short8*)(Vl + (nt * 4 + 1) * 512), oacc[nt], 0, 0, 0);
      oacc[nt] = __builtin_amdgcn_mfma_f32_32x32x16_bf16(
          pf2.v, *(const short8*)(Vl + (nt * 4 + 2) * 512), oacc[nt], 0, 0, 0);
      oacc[nt] = __builtin_amdgcn_mfma_f32_32x32x16_bf16(
          pf3.v, *(const short8*)(Vl + (nt * 4 + 3) * 512), oacc[nt], 0, 0, 0);
    }
    __builtin_amdgcn_s_setprio(0);
  }

  // ---- epilogue: reduce l once; O row q=(r&3)+8*(r>>2)+4*hi ----
  float l_tot = l_run + __shfl_xor(l_run, 32);
  float linv  = 1.0f / l_tot;
#pragma unroll
  for (int r = 0; r < 16; ++r) {
    int qrow = (r & 3) + 8 * (r >> 2) + 4 * hi;
    float il = __shfl(linv, qrow);
    float* orow = Op + (size_t)(q0w + qrow) * Dc + ln;
#pragma unroll
    for (int nt = 0; nt < 4; ++nt)
      orow[nt * 32] = oacc[nt][r] * il;
  }
}

// ===================== fallback (ws too small): R1 kernel =====================
__device__ inline unsigned packbf(float a, float b) {
  return (unsigned)(unsigned short)f2bf(a) | ((unsigned)(unsigned short)f2bf(b) << 16);
}

__global__ __launch_bounds__(256, 2) void attn_fb(
    const float* __restrict__ Qg, const float* __restrict__ Kg,
    const float* __restrict__ Vg, float* __restrict__ Og) {
  __shared__ __align__(16) short Klds[KVBLK * Dc];
  __shared__ __align__(16) short Vt[Dc * 68];
  const int tid = threadIdx.x, wave = tid >> 6, lane = tid & 63;
  const int lg = lane >> 4, lr = lane & 15;
  const int bid = blockIdx.x;
  const int bh = bid & (BH - 1);
  const int qt = 31 - (bid >> 5);
  const int q0w = qt * 64 + wave * 16;
  const float* Qp = Qg + (size_t)bh * Lc * Dc;
  const float* Kp = Kg + (size_t)bh * Lc * Dc;
  const float* Vp = Vg + (size_t)bh * Lc * Dc;
  float* Op = Og + (size_t)bh * Lc * Dc;
  short8 qf[4];
  {
    const float* qrow = Qp + (size_t)(q0w + lr) * Dc;
#pragma unroll
    for (int dc = 0; dc < 4; ++dc) {
      float4 a = *(const float4*)(qrow + dc * 32 + lg * 4);
      float4 b = *(const float4*)(qrow + dc * 32 + 16 + lg * 4);
      short8 v;
      v[0]=f2bf(a.x*SCALE); v[1]=f2bf(a.y*SCALE); v[2]=f2bf(a.z*SCALE); v[3]=f2bf(a.w*SCALE);
      v[4]=f2bf(b.x*SCALE); v[5]=f2bf(b.y*SCALE); v[6]=f2bf(b.z*SCALE); v[7]=f2bf(b.w*SCALE);
      qf[dc] = v;
    }
  }
  const f32x4 zero4 = {0.f,0.f,0.f,0.f};
  float m_run = -1e30f, l_run = 0.0f;
  f32x4 oacc[8];
#pragma unroll
  for (int dt = 0; dt < 8; ++dt) oacc[dt] = zero4;
  const int ntiles = qt + 1, c4 = tid & 31, rK = tid >> 5;
  for (int t = 0; t < ntiles; ++t) {
    const int kv0 = t * KVBLK;
    __syncthreads();
#pragma unroll
    for (int p = 0; p < 8; ++p) {
      int row = rK + p * 8;
      float4 k4 = *(const float4*)(Kp + (size_t)(kv0 + row) * Dc + c4 * 4);
      short4 pk; pk.x=f2bf(k4.x); pk.y=f2bf(k4.y); pk.z=f2bf(k4.z); pk.w=f2bf(k4.w);
      *(short4*)((char*)Klds + row * 256 + ((c4 * 8) ^ ((row & 7) << 4))) = pk;
    }
#pragma unroll
    for (int p = 0; p < 4; ++p) {
      int r0 = rK * 2 + p * 16;
      float4 v0 = *(const float4*)(Vp + (size_t)(kv0 + r0) * Dc + c4 * 4);
      float4 v1 = *(const float4*)(Vp + (size_t)(kv0 + r0 + 1) * Dc + c4 * 4);
      char* vb2 = (char*)Vt + r0 * 2;
      *(unsigned*)(vb2 + (c4*4+0)*136) = packbf(v0.x, v1.x);
      *(unsigned*)(vb2 + (c4*4+1)*136) = packbf(v0.y, v1.y);
      *(unsigned*)(vb2 + (c4*4+2)*136) = packbf(v0.z, v1.z);
      *(unsigned*)(vb2 + (c4*4+3)*136) = packbf(v0.w, v1.w);
    }
    __syncthreads();
    f32x4 st[4];
#pragma unroll
    for (int mt = 0; mt < 4; ++mt) st[mt] = zero4;
#pragma unroll
    for (int dc = 0; dc < 4; ++dc)
#pragma unroll
      for (int mt = 0; mt < 4; ++mt) {
        int row = mt * 16 + lr, sw2 = (row & 7) << 4;
        FragU a;
        a.h[0] = *(short4*)((char*)Klds + row*256 + ((dc*64      + lg*8) ^ sw2));
        a.h[1] = *(short4*)((char*)Klds + row*256 + ((dc*64 + 32 + lg*8) ^ sw2));
        st[mt] = __builtin_amdgcn_mfma_f32_16x16x32_bf16(a.v, qf[dc], st[mt], 0, 0, 0);
      }
    if (t == ntiles - 1) {
      const int qg = q0w + lr;
#pragma unroll
      for (int mt = 0; mt < 4; ++mt)
#pragma unroll
        for (int r = 0; r < 4; ++r)
          if (kv0 + mt * 16 + lg * 4 + r > qg) st[mt][r] = -1e30f;
    }
    float mx = st[0][0];
#pragma unroll
    for (int mt = 0; mt < 4; ++mt)
#pragma unroll
      for (int r = 0; r < 4; ++r) mx = fmaxf(mx, st[mt][r]);
    mx = fmaxf(mx, __shfl_xor(mx, 16));
    mx = fmaxf(mx, __shfl_xor(mx, 32));
    float mnew = fmaxf(m_run, mx);
    float corr = exp2f(m_run - mnew);
    m_run = mnew;
    float pr[4][4]; float rs = 0.0f;
#pragma unroll
    for (int mt = 0; mt < 4; ++mt)
#pragma unroll
      for (int r = 0; r < 4; ++r) { float e = exp2f(st[mt][r] - mnew); pr[mt][r] = e; rs += e; }
    rs += __shfl_xor(rs, 16);
    rs += __shfl_xor(rs, 32);
    l_run = l_run * corr + rs;
#pragma unroll
    for (int r = 0; r < 4; ++r) {
      float c = __shfl(corr, (lane & 48) + lg * 4 + r);
#pragma unroll
      for (int dt = 0; dt < 8; ++dt) oacc[dt][r] *= c;
    }
    short8 pf2[2];
#pragma unroll
    for (int c = 0; c < 2; ++c) {
      short8 v;
      v[0]=f2bf(pr[2*c][0]); v[1]=f2bf(pr[2*c][1]); v[2]=f2bf(pr[2*c][2]); v[3]=f2bf(pr[2*c][3]);
      v[4]=f2bf(pr[2*c+1][0]); v[5]=f2bf(pr[2*c+1][1]); v[6]=f2bf(pr[2*c+1][2]); v[7]=f2bf(pr[2*c+1][3]);
      pf2[c] = v;
    }
#pragma unroll
    for (int dt = 0; dt < 8; ++dt) {
      int rowb = (dt * 16 + lr) * 136;
#pragma unroll
      for (int c = 0; c < 2; ++c) {
        FragU b;
        b.h[0] = *(short4*)((char*)Vt + rowb + c*64      + lg*8);
        b.h[1] = *(short4*)((char*)Vt + rowb + c*64 + 32 + lg*8);
        oacc[dt] = __builtin_amdgcn_mfma_f32_16x16x32_bf16(pf2[c], b.v, oacc[dt], 0, 0, 0);
      }
    }
  }
#pragma unroll
  for (int r = 0; r < 4; ++r) {
    float li = __shfl(l_run, (lane & 48) + lg * 4 + r);
    float inv = 1.0f / li;
    float* orow = Op + (size_t)(q0w + lg * 4 + r) * Dc;
#pragma unroll
    for (int dt = 0; dt < 8; ++dt) orow[dt * 16 + lr] = oacc[dt][r] * inv;
  }
}

} // namespace

extern "C" void kernel_launch(void* const* d_in, const int* in_sizes, int n_in,
                              void* d_out, int out_size, void* d_ws, size_t ws_size,
                              hipStream_t stream) {
  const float* Q = (const float*)d_in[0];
  const float* K = (const float*)d_in[1];
  const float* V = (const float*)d_in[2];
  float* O = (float*)d_out;
  const size_t elems = (size_t)BH * Lc * Dc;          // 8.39M per tensor
  const size_t need  = 2 * elems * sizeof(short);     // 33.5 MB
  if (ws_size >= need) {
    short* Kw = (short*)d_ws;
    short* Vw = Kw + elems;
    conv_kv<<<dim3(4096 + 1024), dim3(256), 0, stream>>>(K, V, Kw, Vw);
    attn_fwd13<<<dim3(BH * NQT), dim3(256), 0, stream>>>(Q, Kw, Vw, O);
  } else {
    attn_fb<<<dim3(BH * NKT), dim3(256), 0, stream>>>(Q, K, V, O);
  }
}